// Round 5
// baseline (386.144 us; speedup 1.0000x reference)
//
#include <hip/hip_runtime.h>

#define NA 4096
#define HS 128
#define CSTR 136   // proj/reduce LDS row stride (bf16 elems)

typedef unsigned short u16;
typedef unsigned long long u64;
using bf16x8  = __attribute__((ext_vector_type(8))) short;
using f32x4   = __attribute__((ext_vector_type(4))) float;
using ushort8 = __attribute__((ext_vector_type(8))) unsigned short;
using u32x4   = __attribute__((ext_vector_type(4))) unsigned;

// 1/sqrt(dk)=0.25 * log2(e) * 0.5 (K-dim duplication in the 16x16x32 MFMA)
#define QSCALE 0.18033688011112042f

static __device__ __forceinline__ u16 f2bf(float f) {
    unsigned u = __builtin_bit_cast(unsigned, f);
    u += 0x7FFFu + ((u >> 16) & 1u);
    return (u16)(u >> 16);
}

// ---------------------------------------------------------------------------
// Kernel 1 (everything before attention, one launch):
//   blocks    0..1023: mask pack -> Mp[row(4096)][word(64)] u64 (lane-pack,
//                      16 independent int4 loads; BW-bound long pole, first)
//   blocks 1024..1407: Q/K/V projections via MFMA; weights self-converted
//                      into LDS in fragment order (cvt_w kernel eliminated)
//   blocks 1408..1423: Wo -> WoF bf16 fragment order (for attn's combine)
//   block        1424: zero cnt[256] (split-K combine counters; also resets
//                      them between graph-replay iterations)
// Outputs:
//   Qbh [head][4096][16]  natural row order
//   Kbh [head][4096][16]  rows PERMUTED within each 64-block by slot(k) so
//       attn's ST MFMA output lands P register-resident for the PV A-operand:
//       slot(k) = ((k>>5)*2+((k>>2)&1))*16 + ((k>>3)&3)*4 + (k&3)
//       => ST[t4] lane (c,q) reg r holds key 32*(t4>>1)+4*(t4&1)+8q+r
//   VtB [kb(64)][dim(128)][key(64)]  (PV B-fragment loads contiguous)
// ---------------------------------------------------------------------------
__global__ __launch_bounds__(256) void proj_pack(
    const float* __restrict__ Xq, const float* __restrict__ Xk, const float* __restrict__ Xv,
    const float* __restrict__ Wq, const float* __restrict__ Wk,
    const float* __restrict__ Wv, const float* __restrict__ Wo,
    const float* __restrict__ bq, const float* __restrict__ bk,
    const float* __restrict__ bv, const int* __restrict__ mask,
    u16* __restrict__ Qbh, u16* __restrict__ Kbh, u16* __restrict__ VtB,
    u64* __restrict__ Mp, u16* __restrict__ WoF, int* __restrict__ cnt)
{
    const int blk = blockIdx.x;
    const int t = threadIdx.x;

    if (blk < 1024) {               // ---- mask pack, per-lane word build
        const int wv = t >> 6, lane = t & 63;
        const int row = blk * 4 + wv;           // one mask row per wave
        const int* lp = mask + (size_t)row * NA + lane * 64;
        int4 v[16];
#pragma unroll
        for (int j = 0; j < 16; ++j) v[j] = *(const int4*)(lp + j * 4);
        u64 word = 0;
#pragma unroll
        for (int j = 0; j < 16; ++j) {
            const u64 nib = (u64)((v[j].x != 0 ? 1u : 0u) | (v[j].y != 0 ? 2u : 0u)
                                | (v[j].z != 0 ? 4u : 0u) | (v[j].w != 0 ? 8u : 0u));
            word |= nib << (4 * j);
        }
        Mp[(size_t)row * 64 + lane] = word;
        return;
    }

    if (blk >= 1408) {              // ---- Wo fragment cvt / counter zero
        if (blk == 1424) {
            if (t < 256) cnt[t] = 0;
            return;
        }
        const int gid = (blk - 1408) * 256 + t;   // 0..4095
        const int off = gid * 4;
        float4 v = *(const float4*)(Wo + off);
        ushort4 o;
        o.x = f2bf(v.x); o.y = f2bf(v.y); o.z = f2bf(v.z); o.w = f2bf(v.w);
        const int j = off >> 7, k0 = off & 127;
        const int j0 = j >> 4, c = j & 15, kk = k0 >> 5, q = (k0 >> 3) & 3;
        *(ushort4*)(WoF + ((j0 * 4 + kk) * 16 + c) * 32 + q * 8 + (k0 & 7)) = o;
        return;
    }

    // ---- projection: blk 1024..1407
    const int pb = blk - 1024;
    const int mat = pb >> 7;
    const float* X = (mat == 0) ? Xq : (mat == 1) ? Xk : Xv;
    const float* Wsrc = (mat == 0) ? Wq : (mat == 1) ? Wk : Wv;
    const float* bsrc = (mat == 0) ? bq : (mat == 1) ? bk : bv;
    const float sc = (mat == 0) ? QSCALE : 1.0f;
    const int r0b = (pb & 127) * 32;

    // Ws: fragment-ordered weights, lane-contiguous: elem (j0,kk,c,q,e) at
    //   (j0*4+kk)*512 + q*128 + c*8 + e   (lane (c,q) reads 16B at lane*16)
    __shared__ __align__(16) u16 Ws[16384];
    __shared__ __align__(16) u16 Xs[32 * CSTR];
    __shared__ __align__(16) u16 Cs[32 * CSTR];

    // self-convert W: thread t covers source elems [t*64, t*64+64)
    {
        const int base = t * 64;
#pragma unroll
        for (int i = 0; i < 16; ++i) {
            const int off = base + i * 4;
            float4 v = *(const float4*)(Wsrc + off);
            ushort4 o;
            o.x = f2bf(v.x * sc); o.y = f2bf(v.y * sc);
            o.z = f2bf(v.z * sc); o.w = f2bf(v.w * sc);
            const int j = off >> 7, k0 = off & 127;
            const int j0 = j >> 4, c2 = j & 15, kk = k0 >> 5, qq = (k0 >> 3) & 3;
            *(ushort4*)(Ws + (j0 * 4 + kk) * 512 + qq * 128 + c2 * 8 + (k0 & 7)) = o;
        }
    }

    // stage X coalesced: thread -> row t>>3, 16 cols at (t&7)*16
    {
        const int r = t >> 3, cb = (t & 7) * 16;
        const float* Xr = X + (size_t)(r0b + r) * HS + cb;
#pragma unroll
        for (int seg = 0; seg < 4; ++seg) {
            float4 f = *(const float4*)(Xr + seg * 4);
            ushort4 u;
            u.x = f2bf(f.x); u.y = f2bf(f.y); u.z = f2bf(f.z); u.w = f2bf(f.w);
            *(ushort4*)(Xs + r * CSTR + cb + seg * 4) = u;
        }
    }
    __syncthreads();

    const int wv = t >> 6, lane = t & 63;
    const int c = lane & 15, q = lane >> 4;
    const int rw = (wv & 1) * 16;        // wave row offset in block
    const int j0b = (wv >> 1) * 4;       // wave col group (4 j0 of 16 cols)

    bf16x8 af[4];
#pragma unroll
    for (int kk = 0; kk < 4; ++kk)
        af[kk] = *(const bf16x8*)(Xs + (rw + c) * CSTR + kk * 32 + q * 8);

    const f32x4 zero = {0.f, 0.f, 0.f, 0.f};
#pragma unroll
    for (int jj = 0; jj < 4; ++jj) {
        const int j0 = j0b + jj;
        f32x4 acc = zero;
#pragma unroll
        for (int kk = 0; kk < 4; ++kk) {
            bf16x8 bf = *(const bf16x8*)(Ws + (j0 * 4 + kk) * 512 + q * 128 + c * 8);
            acc = __builtin_amdgcn_mfma_f32_16x16x32_bf16(af[kk], bf, acc, 0, 0, 0);
        }
        const float bias = bsrc[j0 * 16 + c] * sc;
#pragma unroll
        for (int r = 0; r < 4; ++r)
            Cs[(rw + 4 * q + r) * CSTR + j0 * 16 + c] = f2bf(acc[r] + bias);
    }
    __syncthreads();

    if (mat < 2) {
        u16* dst = (mat == 0) ? Qbh : Kbh;
        const int h8 = t >> 5, r = t & 31;
        const u16* src = Cs + r * CSTR + h8 * 16;
        int drow = r0b + r;
        if (mat == 1) {   // permuted K row slot within the 64-row block
            const int k = (r0b & 32) + r;
            const int slot = ((k >> 5) * 2 + ((k >> 2) & 1)) * 16
                           + ((k >> 3) & 3) * 4 + (k & 3);
            drow = (r0b & ~63) + slot;
        }
        u16* dp = dst + (size_t)h8 * (NA * 16) + (size_t)drow * 16;
        *(bf16x8*)(dp)     = *(const bf16x8*)(src);
        *(bf16x8*)(dp + 8) = *(const bf16x8*)(src + 8);
    } else {
        const int d = t >> 1, s = t & 1;
        const int kb = r0b >> 6, ko = (r0b & 32) + s * 16;
        ushort8 v0, v1;
#pragma unroll
        for (int jj = 0; jj < 8; ++jj) v0[jj] = Cs[(s * 16 + jj) * CSTR + d];
#pragma unroll
        for (int jj = 0; jj < 8; ++jj) v1[jj] = Cs[(s * 16 + 8 + jj) * CSTR + d];
        u16* dp = VtB + (size_t)kb * 8192 + d * 64 + ko;
        *(ushort8*)(dp)     = v0;
        *(ushort8*)(dp + 8) = v1;
    }
}

// ---------------------------------------------------------------------------
// Kernel 2: attention partials + split-K last-block combine.
// Grid (256 tiles, 4 key-splits), 512 thr = 8 waves, wave = one head.
// Main loop identical to the proven round-2/4 kernel (P register-resident via
// the K-row permutation). After writing partials, blocks release-fence and
// atomicAdd cnt[tile]; the last of the 4 split-blocks acquire-fences, reads
// all 4 partials, normalizes, and does the output projection (8 waves = 8 j0
// groups, same math as the old reduce_out) directly to out.
// part[tile][split][head][272] = { O 16x16 f32, l 16 f32 }.
// ---------------------------------------------------------------------------
__global__ __launch_bounds__(512, 4) void attn(
    const u64* __restrict__ Mp,
    const u16* __restrict__ Qbh, const u16* __restrict__ Kbh, const u16* __restrict__ VtB,
    const u16* __restrict__ WoF,
    float* __restrict__ part, int* __restrict__ cnt, float* __restrict__ out)
{
    __shared__ __align__(8)  u64 Mwp[16 * 17];   // [query][word], padded stride
    __shared__ __align__(8)  u64 Mtab[16];       // nibble -> {lo16|hi16} x2 expand
    __shared__ int isLast;
    __shared__ __align__(16) u16 xs[16 * CSTR];  // combine staging

    const int t = threadIdx.x;
    const int h = t >> 6;        // wave = head
    const int lane = t & 63;
    const int c = lane & 15;
    const int q = lane >> 4;
    const int tile = blockIdx.x, split = blockIdx.y;
    const int i0 = tile * 16;
    const int kt0 = split * 1024;

    // stage packed mask words: rows i0..i0+15, words split*16..+15
    if (t < 256) {
        const int row = t >> 4, w = t & 15;
        Mwp[row * 17 + w] = Mp[(size_t)(i0 + row) * 64 + (kt0 >> 6) + w];
    }
    if (t < 16) {
        const unsigned lo = ((t & 1) ? 0xFFFFu : 0u) | ((t & 2) ? 0xFFFF0000u : 0u);
        const unsigned hi = ((t & 4) ? 0xFFFFu : 0u) | ((t & 8) ? 0xFFFF0000u : 0u);
        Mtab[t] = (u64)lo | ((u64)hi << 32);
    }

    const u16* Qh = Qbh + (size_t)h * (NA * 16);
    const u16* Kh = Kbh + (size_t)h * (NA * 16);

    // Q B-fragment (K-halves duplicated; x2 folded into QSCALE); contiguous.
    const bf16x8 qf = *(const bf16x8*)(Qh + (size_t)(i0 + c) * 16 + (q & 1) * 8);

    // ones B-fragment for the lsum MFMA (all lanes = 1.0bf16)
    bf16x8 ones;
#pragma unroll
    for (int i = 0; i < 8; ++i) ones[i] = (short)0x3F80;

    __syncthreads();

    const f32x4 zero = {0.f, 0.f, 0.f, 0.f};
    f32x4 Oacc = zero;
    f32x4 Lacc = zero;

    // prologue: kf for iter 0 (rows are permuted slots; addresses natural)
    bf16x8 kf[4];
#pragma unroll
    for (int t4 = 0; t4 < 4; ++t4)
        kf[t4] = *(const bf16x8*)(Kh + (size_t)(kt0 + t4 * 16 + c) * 16 + (q & 1) * 8);

#pragma unroll 1
    for (int it = 0; it < 16; ++it) {
        const int kt = kt0 + it * 64;
        const u16* Vb = VtB + (size_t)(kt >> 6) * 8192 + (h * 16 + c) * 64;

        // V B-fragments (contiguous 1KB per load across the wave)
        bf16x8 vf0 = *(const bf16x8*)(Vb + q * 8);
        bf16x8 vf1 = *(const bf16x8*)(Vb + 32 + q * 8);

        // S^T tiles; permuted K => lane (c,q) reg r = S[q_row c][key B(t4)+8q+r]
        f32x4 ST[4];
        __builtin_amdgcn_s_setprio(1);
#pragma unroll
        for (int t4 = 0; t4 < 4; ++t4)
            ST[t4] = __builtin_amdgcn_mfma_f32_16x16x32_bf16(kf[t4], qf, zero, 0, 0, 0);
        __builtin_amdgcn_s_setprio(0);

        // prefetch next iter's kf (wraps to kt0 on last iter; data unused)
        const int ktn = kt0 + ((it + 1) & 15) * 64;
#pragma unroll
        for (int t4 = 0; t4 < 4; ++t4)
            kf[t4] = *(const bf16x8*)(Kh + (size_t)(ktn + t4 * 16 + c) * 16 + (q & 1) * 8);

        // mask bits, natural order: key B(t4)+8q+r; B = 32*(t4>>1)+4*(t4&1)
        const u64 w = Mwp[c * 17 + it];
        const unsigned wa = (unsigned)(w >> (8 * q));          // keys 8q+...
        const unsigned wb = (unsigned)(w >> (32 + 8 * q));     // keys 32+8q+...

        unsigned pl[4], ph[4];
#pragma unroll
        for (int t4 = 0; t4 < 4; ++t4) {
            const unsigned nib = (((t4 & 2) ? wb : wa) >> ((t4 & 1) * 4)) & 15u;
            float p0 = __builtin_amdgcn_exp2f(ST[t4][0]);
            float p1 = __builtin_amdgcn_exp2f(ST[t4][1]);
            float p2 = __builtin_amdgcn_exp2f(ST[t4][2]);
            float p3 = __builtin_amdgcn_exp2f(ST[t4][3]);
            unsigned lo, hi;
            asm("v_cvt_pk_bf16_f32 %0, %1, %2" : "=v"(lo) : "v"(p0), "v"(p1));
            asm("v_cvt_pk_bf16_f32 %0, %1, %2" : "=v"(hi) : "v"(p2), "v"(p3));
            const u64 mex = Mtab[nib];           // conflict-light 16-entry table
            pl[t4] = lo & (unsigned)mex;
            ph[t4] = hi & (unsigned)(mex >> 32);
        }
        const u32x4 a0 = { pl[0], ph[0], pl[1], ph[1] };   // keys 8q+0..7
        const u32x4 a1 = { pl[2], ph[2], pl[3], ph[3] };   // keys 32+8q+0..7
        const bf16x8 pf0 = __builtin_bit_cast(bf16x8, a0);
        const bf16x8 pf1 = __builtin_bit_cast(bf16x8, a1);

        // O += P @ V ; L += P @ ones (masked row-sums)
        __builtin_amdgcn_s_setprio(1);
        Oacc = __builtin_amdgcn_mfma_f32_16x16x32_bf16(pf0, vf0, Oacc, 0, 0, 0);
        Oacc = __builtin_amdgcn_mfma_f32_16x16x32_bf16(pf1, vf1, Oacc, 0, 0, 0);
        Lacc = __builtin_amdgcn_mfma_f32_16x16x32_bf16(pf0, ones, Lacc, 0, 0, 0);
        Lacc = __builtin_amdgcn_mfma_f32_16x16x32_bf16(pf1, ones, Lacc, 0, 0, 0);
        __builtin_amdgcn_s_setprio(0);
    }

    float* base = part + (size_t)((tile * 4 + split) * 8 + h) * 272;
#pragma unroll
    for (int r = 0; r < 4; ++r)
        base[(4 * q + r) * 16 + c] = Oacc[r];
    // Lacc: lane (c,q) reg r holds l[4q+r] (all c identical); c==0 lanes write
    if (c == 0) {
#pragma unroll
        for (int r = 0; r < 4; ++r)
            base[256 + 4 * q + r] = Lacc[r];
    }

    // ---- split-K combine: last block of the 4 splits finishes the tile
    __threadfence();                               // release partials
    __syncthreads();                               // all waves' stores issued
    if (t == 0) isLast = (atomicAdd(&cnt[tile], 1) == 3);
    __syncthreads();
    if (!isLast) return;
    __threadfence();                               // acquire others' partials

    const float* Pt = part + (size_t)tile * 4 * 8 * 272;
    if (t < 256) {
        const int i = t >> 4, d = t & 15;
#pragma unroll
        for (int hh = 0; hh < 8; ++hh) {
            float os = 0.f, ls = 0.f;
#pragma unroll
            for (int s = 0; s < 4; ++s) {
                const float* b = Pt + (size_t)(s * 8 + hh) * 272;
                os += b[i * 16 + d];
                ls += b[256 + i];
            }
            xs[i * CSTR + hh * 16 + d] = f2bf(os / ls);
        }
    }
    __syncthreads();

    // output projection: 8 waves, wave h handles j0 = h
    bf16x8 af[4];
#pragma unroll
    for (int kk = 0; kk < 4; ++kk)
        af[kk] = *(const bf16x8*)(xs + c * CSTR + kk * 32 + q * 8);

    f32x4 acc = zero;
#pragma unroll
    for (int kk = 0; kk < 4; ++kk) {
        bf16x8 bf = *(const bf16x8*)(WoF + (h * 4 + kk) * 512 + c * 32 + q * 8);
        acc = __builtin_amdgcn_mfma_f32_16x16x32_bf16(af[kk], bf, acc, 0, 0, 0);
    }
#pragma unroll
    for (int r = 0; r < 4; ++r)
        out[(size_t)(i0 + 4 * q + r) * HS + h * 16 + c] = acc[r];
}

extern "C" void kernel_launch(void* const* d_in, const int* in_sizes, int n_in,
                              void* d_out, int out_size, void* d_ws, size_t ws_size,
                              hipStream_t stream) {
    const float* query = (const float*)d_in[0];
    const float* key   = (const float*)d_in[1];
    const float* value = (const float*)d_in[2];
    const int*   mask  = (const int*)d_in[3];
    const float* Wq    = (const float*)d_in[4];
    const float* bq    = (const float*)d_in[5];
    const float* Wk    = (const float*)d_in[6];
    const float* bk    = (const float*)d_in[7];
    const float* Wv    = (const float*)d_in[8];
    const float* bv    = (const float*)d_in[9];
    const float* Wo    = (const float*)d_in[10];

    u16* Qbh = (u16*)d_ws;                     // 1 MB  [8][4096][16]
    u16* Kbh = Qbh + (size_t)NA * HS;          // 1 MB  [8][4096][16] (permuted)
    u16* VtB = Kbh + (size_t)NA * HS;          // 1 MB  [64][128][64]
    u16* WoF = VtB + (size_t)NA * HS;          // 32 KB (Wo fragments)
    u64*  Mp  = (u64*)(WoF + 16384);           // 2 MB   [4096][64] packed mask
    int*  cnt = (int*)(Mp + (size_t)NA * 64);  // 1 KB  [256] combine counters
    float* partb = (float*)(cnt + 256);        // 256*4*8*272 f32 = 8.9 MB

    proj_pack<<<1425, 256, 0, stream>>>(query, key, value, Wq, Wk, Wv, Wo,
                                        bq, bk, bv, mask,
                                        Qbh, Kbh, VtB, Mp, WoF, cnt);
    attn<<<dim3(256, 4), 512, 0, stream>>>(Mp, Qbh, Kbh, VtB, WoF,
                                           partb, cnt, (float*)d_out);
}

// Round 7
// 172.277 us; speedup vs baseline: 2.2414x; 2.2414x over previous
//
#include <hip/hip_runtime.h>

#define NA 4096
#define HS 128
#define CSTR 136   // proj/reduce LDS row stride (bf16 elems)

typedef unsigned short u16;
typedef unsigned long long u64;
using bf16x8  = __attribute__((ext_vector_type(8))) short;
using f32x4   = __attribute__((ext_vector_type(4))) float;
using ushort8 = __attribute__((ext_vector_type(8))) unsigned short;
using u32x4   = __attribute__((ext_vector_type(4))) unsigned;

// 1/sqrt(dk)=0.25 * log2(e) * 0.5 (K-dim duplication in the 16x16x32 MFMA)
#define QSCALE 0.18033688011112042f

static __device__ __forceinline__ u16 f2bf(float f) {
    unsigned u = __builtin_bit_cast(unsigned, f);
    u += 0x7FFFu + ((u >> 16) & 1u);
    return (u16)(u >> 16);
}

// ---------------------------------------------------------------------------
// Kernel 1 (everything before attention, one launch; PROVEN round 5):
//   blocks    0..1023: mask pack -> Mp[row(4096)][word(64)] u64 (lane-pack,
//                      16 independent int4 loads; BW-bound long pole, first)
//   blocks 1024..1407: Q/K/V projections via MFMA; weights self-converted
//                      into LDS in fragment order
//   blocks 1408..1423: Wo -> WoF bf16 fragment order (for reduce_out)
// Outputs:
//   Qbh [head][4096][16]  natural row order
//   Kbh [head][4096][16]  rows PERMUTED within each 64-block by slot(k) so
//       attn's ST MFMA output lands P register-resident for the PV A-operand:
//       slot(k) = ((k>>5)*2+((k>>2)&1))*16 + ((k>>3)&3)*4 + (k&3)
//       => ST[t4] lane (c,q) reg r holds key 32*(t4>>1)+4*(t4&1)+8q+r
//   VtB [kb(64)][dim(128)][key(64)]  (PV B-fragment loads contiguous)
// ---------------------------------------------------------------------------
__global__ __launch_bounds__(256) void proj_pack(
    const float* __restrict__ Xq, const float* __restrict__ Xk, const float* __restrict__ Xv,
    const float* __restrict__ Wq, const float* __restrict__ Wk,
    const float* __restrict__ Wv, const float* __restrict__ Wo,
    const float* __restrict__ bq, const float* __restrict__ bk,
    const float* __restrict__ bv, const int* __restrict__ mask,
    u16* __restrict__ Qbh, u16* __restrict__ Kbh, u16* __restrict__ VtB,
    u64* __restrict__ Mp, u16* __restrict__ WoF)
{
    const int blk = blockIdx.x;
    const int t = threadIdx.x;

    if (blk < 1024) {               // ---- mask pack, per-lane word build
        const int wv = t >> 6, lane = t & 63;
        const int row = blk * 4 + wv;           // one mask row per wave
        const int* lp = mask + (size_t)row * NA + lane * 64;
        int4 v[16];
#pragma unroll
        for (int j = 0; j < 16; ++j) v[j] = *(const int4*)(lp + j * 4);
        u64 word = 0;
#pragma unroll
        for (int j = 0; j < 16; ++j) {
            const u64 nib = (u64)((v[j].x != 0 ? 1u : 0u) | (v[j].y != 0 ? 2u : 0u)
                                | (v[j].z != 0 ? 4u : 0u) | (v[j].w != 0 ? 8u : 0u));
            word |= nib << (4 * j);
        }
        Mp[(size_t)row * 64 + lane] = word;
        return;
    }

    if (blk >= 1408) {              // ---- Wo fragment cvt
        const int gid = (blk - 1408) * 256 + t;   // 0..4095
        const int off = gid * 4;
        float4 v = *(const float4*)(Wo + off);
        ushort4 o;
        o.x = f2bf(v.x); o.y = f2bf(v.y); o.z = f2bf(v.z); o.w = f2bf(v.w);
        const int j = off >> 7, k0 = off & 127;
        const int j0 = j >> 4, c = j & 15, kk = k0 >> 5, q = (k0 >> 3) & 3;
        *(ushort4*)(WoF + ((j0 * 4 + kk) * 16 + c) * 32 + q * 8 + (k0 & 7)) = o;
        return;
    }

    // ---- projection: blk 1024..1407
    const int pb = blk - 1024;
    const int mat = pb >> 7;
    const float* X = (mat == 0) ? Xq : (mat == 1) ? Xk : Xv;
    const float* Wsrc = (mat == 0) ? Wq : (mat == 1) ? Wk : Wv;
    const float* bsrc = (mat == 0) ? bq : (mat == 1) ? bk : bv;
    const float sc = (mat == 0) ? QSCALE : 1.0f;
    const int r0b = (pb & 127) * 32;

    // Ws: fragment-ordered weights, lane-contiguous: elem (j0,kk,c,q,e) at
    //   (j0*4+kk)*512 + q*128 + c*8 + e   (lane (c,q) reads 16B at lane*16)
    __shared__ __align__(16) u16 Ws[16384];
    __shared__ __align__(16) u16 Xs[32 * CSTR];
    __shared__ __align__(16) u16 Cs[32 * CSTR];

    // self-convert W: thread t covers source elems [t*64, t*64+64)
    {
        const int base = t * 64;
#pragma unroll
        for (int i = 0; i < 16; ++i) {
            const int off = base + i * 4;
            float4 v = *(const float4*)(Wsrc + off);
            ushort4 o;
            o.x = f2bf(v.x * sc); o.y = f2bf(v.y * sc);
            o.z = f2bf(v.z * sc); o.w = f2bf(v.w * sc);
            const int j = off >> 7, k0 = off & 127;
            const int j0 = j >> 4, c2 = j & 15, kk = k0 >> 5, qq = (k0 >> 3) & 3;
            *(ushort4*)(Ws + (j0 * 4 + kk) * 512 + qq * 128 + c2 * 8 + (k0 & 7)) = o;
        }
    }

    // stage X coalesced: thread -> row t>>3, 16 cols at (t&7)*16
    {
        const int r = t >> 3, cb = (t & 7) * 16;
        const float* Xr = X + (size_t)(r0b + r) * HS + cb;
#pragma unroll
        for (int seg = 0; seg < 4; ++seg) {
            float4 f = *(const float4*)(Xr + seg * 4);
            ushort4 u;
            u.x = f2bf(f.x); u.y = f2bf(f.y); u.z = f2bf(f.z); u.w = f2bf(f.w);
            *(ushort4*)(Xs + r * CSTR + cb + seg * 4) = u;
        }
    }
    __syncthreads();

    const int wv = t >> 6, lane = t & 63;
    const int c = lane & 15, q = lane >> 4;
    const int rw = (wv & 1) * 16;        // wave row offset in block
    const int j0b = (wv >> 1) * 4;       // wave col group (4 j0 of 16 cols)

    bf16x8 af[4];
#pragma unroll
    for (int kk = 0; kk < 4; ++kk)
        af[kk] = *(const bf16x8*)(Xs + (rw + c) * CSTR + kk * 32 + q * 8);

    const f32x4 zero = {0.f, 0.f, 0.f, 0.f};
#pragma unroll
    for (int jj = 0; jj < 4; ++jj) {
        const int j0 = j0b + jj;
        f32x4 acc = zero;
#pragma unroll
        for (int kk = 0; kk < 4; ++kk) {
            bf16x8 bf = *(const bf16x8*)(Ws + (j0 * 4 + kk) * 512 + q * 128 + c * 8);
            acc = __builtin_amdgcn_mfma_f32_16x16x32_bf16(af[kk], bf, acc, 0, 0, 0);
        }
        const float bias = bsrc[j0 * 16 + c] * sc;
#pragma unroll
        for (int r = 0; r < 4; ++r)
            Cs[(rw + 4 * q + r) * CSTR + j0 * 16 + c] = f2bf(acc[r] + bias);
    }
    __syncthreads();

    if (mat < 2) {
        u16* dst = (mat == 0) ? Qbh : Kbh;
        const int h8 = t >> 5, r = t & 31;
        const u16* src = Cs + r * CSTR + h8 * 16;
        int drow = r0b + r;
        if (mat == 1) {   // permuted K row slot within the 64-row block
            const int k = (r0b & 32) + r;
            const int slot = ((k >> 5) * 2 + ((k >> 2) & 1)) * 16
                           + ((k >> 3) & 3) * 4 + (k & 3);
            drow = (r0b & ~63) + slot;
        }
        u16* dp = dst + (size_t)h8 * (NA * 16) + (size_t)drow * 16;
        *(bf16x8*)(dp)     = *(const bf16x8*)(src);
        *(bf16x8*)(dp + 8) = *(const bf16x8*)(src + 8);
    } else {
        const int d = t >> 1, s = t & 1;
        const int kb = r0b >> 6, ko = (r0b & 32) + s * 16;
        ushort8 v0, v1;
#pragma unroll
        for (int jj = 0; jj < 8; ++jj) v0[jj] = Cs[(s * 16 + jj) * CSTR + d];
#pragma unroll
        for (int jj = 0; jj < 8; ++jj) v1[jj] = Cs[(s * 16 + 8 + jj) * CSTR + d];
        u16* dp = VtB + (size_t)kb * 8192 + d * 64 + ko;
        *(ushort8*)(dp)     = v0;
        *(ushort8*)(dp + 8) = v1;
    }
}

// ---------------------------------------------------------------------------
// Kernel 2: attention partials — EXACT round-2/4 body (passed r2, r4, r5).
// FROZEN: two semantically-equivalent rewrites of this loop (r3, r6) broke
// numerics; do not restructure register lifetimes here.
// Grid (256 tiles, 4 key-splits), 512 thr = 8 waves, wave = one head.
// P register-resident via the K-row permutation. Per iter: 4 ST MFMA ->
// 16 exp2 -> 8 cvt_pk -> mask AND -> 4 PV/L MFMA, all in regs.
// part[tile][split][head][272] = { O 16x16 f32, l 16 f32 }.
// ---------------------------------------------------------------------------
__global__ __launch_bounds__(512, 4) void attn(
    const u64* __restrict__ Mp,
    const u16* __restrict__ Qbh, const u16* __restrict__ Kbh, const u16* __restrict__ VtB,
    float* __restrict__ part)
{
    __shared__ __align__(8)  u64 Mwp[16 * 17];   // [query][word], padded stride
    __shared__ __align__(8)  u64 Mtab[16];       // nibble -> {lo16|hi16} x2 expand

    const int t = threadIdx.x;
    const int h = t >> 6;        // wave = head
    const int lane = t & 63;
    const int c = lane & 15;
    const int q = lane >> 4;
    const int tile = blockIdx.x, split = blockIdx.y;
    const int i0 = tile * 16;
    const int kt0 = split * 1024;

    // stage packed mask words: rows i0..i0+15, words split*16..+15
    if (t < 256) {
        const int row = t >> 4, w = t & 15;
        Mwp[row * 17 + w] = Mp[(size_t)(i0 + row) * 64 + (kt0 >> 6) + w];
    }
    if (t < 16) {
        const unsigned lo = ((t & 1) ? 0xFFFFu : 0u) | ((t & 2) ? 0xFFFF0000u : 0u);
        const unsigned hi = ((t & 4) ? 0xFFFFu : 0u) | ((t & 8) ? 0xFFFF0000u : 0u);
        Mtab[t] = (u64)lo | ((u64)hi << 32);
    }

    const u16* Qh = Qbh + (size_t)h * (NA * 16);
    const u16* Kh = Kbh + (size_t)h * (NA * 16);

    // Q B-fragment (K-halves duplicated; x2 folded into QSCALE); contiguous.
    const bf16x8 qf = *(const bf16x8*)(Qh + (size_t)(i0 + c) * 16 + (q & 1) * 8);

    // ones B-fragment for the lsum MFMA (all lanes = 1.0bf16)
    bf16x8 ones;
#pragma unroll
    for (int i = 0; i < 8; ++i) ones[i] = (short)0x3F80;

    __syncthreads();

    const f32x4 zero = {0.f, 0.f, 0.f, 0.f};
    f32x4 Oacc = zero;
    f32x4 Lacc = zero;

    // prologue: kf for iter 0 (rows are permuted slots; addresses natural)
    bf16x8 kf[4];
#pragma unroll
    for (int t4 = 0; t4 < 4; ++t4)
        kf[t4] = *(const bf16x8*)(Kh + (size_t)(kt0 + t4 * 16 + c) * 16 + (q & 1) * 8);

#pragma unroll 1
    for (int it = 0; it < 16; ++it) {
        const int kt = kt0 + it * 64;
        const u16* Vb = VtB + (size_t)(kt >> 6) * 8192 + (h * 16 + c) * 64;

        // V B-fragments (contiguous 1KB per load across the wave)
        bf16x8 vf0 = *(const bf16x8*)(Vb + q * 8);
        bf16x8 vf1 = *(const bf16x8*)(Vb + 32 + q * 8);

        // S^T tiles; permuted K => lane (c,q) reg r = S[q_row c][key B(t4)+8q+r]
        f32x4 ST[4];
        __builtin_amdgcn_s_setprio(1);
#pragma unroll
        for (int t4 = 0; t4 < 4; ++t4)
            ST[t4] = __builtin_amdgcn_mfma_f32_16x16x32_bf16(kf[t4], qf, zero, 0, 0, 0);
        __builtin_amdgcn_s_setprio(0);

        // prefetch next iter's kf (wraps to kt0 on last iter; data unused)
        const int ktn = kt0 + ((it + 1) & 15) * 64;
#pragma unroll
        for (int t4 = 0; t4 < 4; ++t4)
            kf[t4] = *(const bf16x8*)(Kh + (size_t)(ktn + t4 * 16 + c) * 16 + (q & 1) * 8);

        // mask bits, natural order: key B(t4)+8q+r; B = 32*(t4>>1)+4*(t4&1)
        const u64 w = Mwp[c * 17 + it];
        const unsigned wa = (unsigned)(w >> (8 * q));          // keys 8q+...
        const unsigned wb = (unsigned)(w >> (32 + 8 * q));     // keys 32+8q+...

        unsigned pl[4], ph[4];
#pragma unroll
        for (int t4 = 0; t4 < 4; ++t4) {
            const unsigned nib = (((t4 & 2) ? wb : wa) >> ((t4 & 1) * 4)) & 15u;
            float p0 = __builtin_amdgcn_exp2f(ST[t4][0]);
            float p1 = __builtin_amdgcn_exp2f(ST[t4][1]);
            float p2 = __builtin_amdgcn_exp2f(ST[t4][2]);
            float p3 = __builtin_amdgcn_exp2f(ST[t4][3]);
            unsigned lo, hi;
            asm("v_cvt_pk_bf16_f32 %0, %1, %2" : "=v"(lo) : "v"(p0), "v"(p1));
            asm("v_cvt_pk_bf16_f32 %0, %1, %2" : "=v"(hi) : "v"(p2), "v"(p3));
            const u64 mex = Mtab[nib];           // conflict-light 16-entry table
            pl[t4] = lo & (unsigned)mex;
            ph[t4] = hi & (unsigned)(mex >> 32);
        }
        const u32x4 a0 = { pl[0], ph[0], pl[1], ph[1] };   // keys 8q+0..7
        const u32x4 a1 = { pl[2], ph[2], pl[3], ph[3] };   // keys 32+8q+0..7
        const bf16x8 pf0 = __builtin_bit_cast(bf16x8, a0);
        const bf16x8 pf1 = __builtin_bit_cast(bf16x8, a1);

        // O += P @ V ; L += P @ ones (masked row-sums)
        __builtin_amdgcn_s_setprio(1);
        Oacc = __builtin_amdgcn_mfma_f32_16x16x32_bf16(pf0, vf0, Oacc, 0, 0, 0);
        Oacc = __builtin_amdgcn_mfma_f32_16x16x32_bf16(pf1, vf1, Oacc, 0, 0, 0);
        Lacc = __builtin_amdgcn_mfma_f32_16x16x32_bf16(pf0, ones, Lacc, 0, 0, 0);
        Lacc = __builtin_amdgcn_mfma_f32_16x16x32_bf16(pf1, ones, Lacc, 0, 0, 0);
        __builtin_amdgcn_s_setprio(0);
    }

    float* base = part + (size_t)((tile * 4 + split) * 8 + h) * 272;
#pragma unroll
    for (int r = 0; r < 4; ++r)
        base[(4 * q + r) * 16 + c] = Oacc[r];
    // Lacc: lane (c,q) reg r holds l[4q+r] (all c identical); c==0 lanes write
    if (c == 0) {
#pragma unroll
        for (int r = 0; r < 4; ++r)
            base[256 + 4 * q + r] = Lacc[r];
    }
}

// ---------------------------------------------------------------------------
// Kernel 3: combine 4 split partials, normalize, output projection via MFMA.
// (round-4 proven body; WoF fragment table, read path proven round 5)
// ---------------------------------------------------------------------------
__global__ __launch_bounds__(256) void reduce_out(
    const float* __restrict__ part, const u16* __restrict__ WoF,
    float* __restrict__ out)
{
    __shared__ __align__(16) u16 xs[16 * CSTR];

    const int t = threadIdx.x;
    const int tile = blockIdx.x;
    const int i0 = tile * 16;
    const float* Pt = part + (size_t)tile * 4 * 8 * 272;

    {
        const int i = t >> 4, d = t & 15;
#pragma unroll
        for (int h = 0; h < 8; ++h) {
            float os = 0.f, ls = 0.f;
#pragma unroll
            for (int s = 0; s < 4; ++s) {
                const float* b = Pt + (size_t)(s * 8 + h) * 272;
                os += b[i * 16 + d];
                ls += b[256 + i];
            }
            xs[i * CSTR + h * 16 + d] = f2bf(os / ls);
        }
    }
    __syncthreads();

    const int wv = t >> 6, lane = t & 63;
    const int c = lane & 15, q = lane >> 4;

    bf16x8 af[4];
#pragma unroll
    for (int kk = 0; kk < 4; ++kk)
        af[kk] = *(const bf16x8*)(xs + c * CSTR + kk * 32 + q * 8);

    const f32x4 zero = {0.f, 0.f, 0.f, 0.f};
#pragma unroll
    for (int jj = 0; jj < 2; ++jj) {
        const int j0 = wv * 2 + jj;
        f32x4 acc = zero;
#pragma unroll
        for (int kk = 0; kk < 4; ++kk) {
            bf16x8 bf = *(const bf16x8*)(WoF + (j0 * 4 + kk) * 512 + c * 32 + q * 8);
            acc = __builtin_amdgcn_mfma_f32_16x16x32_bf16(af[kk], bf, acc, 0, 0, 0);
        }
#pragma unroll
        for (int r = 0; r < 4; ++r)
            out[(size_t)(i0 + 4 * q + r) * HS + j0 * 16 + c] = acc[r];
    }
}

extern "C" void kernel_launch(void* const* d_in, const int* in_sizes, int n_in,
                              void* d_out, int out_size, void* d_ws, size_t ws_size,
                              hipStream_t stream) {
    const float* query = (const float*)d_in[0];
    const float* key   = (const float*)d_in[1];
    const float* value = (const float*)d_in[2];
    const int*   mask  = (const int*)d_in[3];
    const float* Wq    = (const float*)d_in[4];
    const float* bq    = (const float*)d_in[5];
    const float* Wk    = (const float*)d_in[6];
    const float* bk    = (const float*)d_in[7];
    const float* Wv    = (const float*)d_in[8];
    const float* bv    = (const float*)d_in[9];
    const float* Wo    = (const float*)d_in[10];

    u16* Qbh = (u16*)d_ws;                     // 1 MB  [8][4096][16]
    u16* Kbh = Qbh + (size_t)NA * HS;          // 1 MB  [8][4096][16] (permuted)
    u16* VtB = Kbh + (size_t)NA * HS;          // 1 MB  [64][128][64]
    u16* WoF = VtB + (size_t)NA * HS;          // 32 KB (Wo fragments)
    u64*  Mp  = (u64*)(WoF + 16384);           // 2 MB   [4096][64] packed mask
    float* partb = (float*)(Mp + (size_t)NA * 64);  // 256*4*8*272 f32 = 8.9 MB

    proj_pack<<<1424, 256, 0, stream>>>(query, key, value, Wq, Wk, Wv, Wo,
                                        bq, bk, bv, mask,
                                        Qbh, Kbh, VtB, Mp, WoF);
    attn<<<dim3(256, 4), 512, 0, stream>>>(Mp, Qbh, Kbh, VtB, partb);
    reduce_out<<<256, 256, 0, stream>>>(partb, WoF, (float*)d_out);
}

// Round 8
// 170.760 us; speedup vs baseline: 2.2613x; 1.0089x over previous
//
#include <hip/hip_runtime.h>

#define NA 4096
#define HS 128
#define CSTR 136   // proj/reduce LDS row stride (bf16 elems)

typedef unsigned short u16;
typedef unsigned long long u64;
using bf16x8  = __attribute__((ext_vector_type(8))) short;
using f32x4   = __attribute__((ext_vector_type(4))) float;
using ushort8 = __attribute__((ext_vector_type(8))) unsigned short;
using u32x4   = __attribute__((ext_vector_type(4))) unsigned;

// 1/sqrt(dk)=0.25 * log2(e) * 0.5 (K-dim duplication in the 16x16x32 MFMA)
#define QSCALE 0.18033688011112042f

static __device__ __forceinline__ u16 f2bf(float f) {
    unsigned u = __builtin_bit_cast(unsigned, f);
    u += 0x7FFFu + ((u >> 16) & 1u);
    return (u16)(u >> 16);
}

// ---------------------------------------------------------------------------
// Kernel 1 (everything before attention, one launch):
//   blocks    0..1023: mask pack -> Mp[row(4096)][word(64)] u64.
//     r8: COALESCED loads (lane l, chunk ch reads int4 at mrow[ch*256+l*4];
//     wave = contiguous 1KB/instr, 16 lines vs 64 strided) -> nibble ->
//     LDS byte transpose (reuses Xs storage) -> lane reads 16 contiguous
//     nibble-bytes (b128) -> u64 assemble. Bit layout IDENTICAL to r4/r7:
//     Mp[row][w] bit j  <-  mask[row][w*64+j].
//   blocks 1024..1407: Q/K/V projections via MFMA; weights self-converted
//                      into LDS in fragment order (proven r5/r7)
//   blocks 1408..1423: Wo -> WoF bf16 fragment order (for reduce_out)
// Outputs:
//   Qbh [head][4096][16]  natural row order
//   Kbh [head][4096][16]  rows PERMUTED within each 64-block by slot(k) so
//       attn's ST MFMA output lands P register-resident for the PV A-operand:
//       slot(k) = ((k>>5)*2+((k>>2)&1))*16 + ((k>>3)&3)*4 + (k&3)
//       => ST[t4] lane (c,q) reg r holds key 32*(t4>>1)+4*(t4&1)+8q+r
//   VtB [kb(64)][dim(128)][key(64)]  (PV B-fragment loads contiguous)
// ---------------------------------------------------------------------------
__global__ __launch_bounds__(256) void proj_pack(
    const float* __restrict__ Xq, const float* __restrict__ Xk, const float* __restrict__ Xv,
    const float* __restrict__ Wq, const float* __restrict__ Wk,
    const float* __restrict__ Wv, const float* __restrict__ Wo,
    const float* __restrict__ bq, const float* __restrict__ bk,
    const float* __restrict__ bv, const int* __restrict__ mask,
    u16* __restrict__ Qbh, u16* __restrict__ Kbh, u16* __restrict__ VtB,
    u64* __restrict__ Mp, u16* __restrict__ WoF)
{
    const int blk = blockIdx.x;
    const int t = threadIdx.x;

    // Shared at kernel scope so the pack branch can reuse Xs storage
    // (no LDS growth -> proj occupancy unchanged).
    __shared__ __align__(16) u16 Ws[16384];
    __shared__ __align__(16) u16 Xs[32 * CSTR];
    __shared__ __align__(16) u16 Cs[32 * CSTR];

    if (blk < 1024) {               // ---- mask pack, coalesced + LDS transpose
        const int wv = t >> 6, lane = t & 63;
        const int row = blk * 4 + wv;           // one mask row per wave
        const int* mrow = mask + (size_t)row * NA;

        // 16 coalesced int4 loads: chunk ch covers ints [ch*256, ch*256+256)
        int4 v[16];
#pragma unroll
        for (int ch = 0; ch < 16; ++ch)
            v[ch] = *(const int4*)(mrow + ch * 256 + lane * 4);

        // nibble for ints [ch*256 + lane*4, +4) -> LDS byte (global nibble
        // index n = ch*64 + lane; nibL[n] covers ints [4n, 4n+4))
        unsigned char* nibL = (unsigned char*)Xs + wv * 1024;
#pragma unroll
        for (int ch = 0; ch < 16; ++ch) {
            const unsigned nib = (v[ch].x != 0 ? 1u : 0u) | (v[ch].y != 0 ? 2u : 0u)
                               | (v[ch].z != 0 ? 4u : 0u) | (v[ch].w != 0 ? 8u : 0u);
            nibL[ch * 64 + lane] = (unsigned char)nib;
        }
        // per-wave write->read dependency only (no barrier needed)

        // lane assembles word `lane`: bytes [lane*16, lane*16+16) = ints
        // [lane*64, lane*64+64); bit 4i+k of word <- byte i bit k.
        const uint4 b16 = *(const uint4*)(nibL + lane * 16);
        unsigned z[4];
        {
            const unsigned xs4[4] = { b16.x, b16.y, b16.z, b16.w };
#pragma unroll
            for (int i = 0; i < 4; ++i) {
                unsigned x = xs4[i];
                x = (x | (x >> 4)) & 0x00FF00FFu;
                x = (x | (x >> 8)) & 0x0000FFFFu;
                z[i] = x;
            }
        }
        const u64 word = (u64)(z[0] | (z[1] << 16))
                       | ((u64)(z[2] | (z[3] << 16)) << 32);
        Mp[(size_t)row * 64 + lane] = word;
        return;
    }

    if (blk >= 1408) {              // ---- Wo fragment cvt
        const int gid = (blk - 1408) * 256 + t;   // 0..4095
        const int off = gid * 4;
        float4 v = *(const float4*)(Wo + off);
        ushort4 o;
        o.x = f2bf(v.x); o.y = f2bf(v.y); o.z = f2bf(v.z); o.w = f2bf(v.w);
        const int j = off >> 7, k0 = off & 127;
        const int j0 = j >> 4, c = j & 15, kk = k0 >> 5, q = (k0 >> 3) & 3;
        *(ushort4*)(WoF + ((j0 * 4 + kk) * 16 + c) * 32 + q * 8 + (k0 & 7)) = o;
        return;
    }

    // ---- projection: blk 1024..1407
    const int pb = blk - 1024;
    const int mat = pb >> 7;
    const float* X = (mat == 0) ? Xq : (mat == 1) ? Xk : Xv;
    const float* Wsrc = (mat == 0) ? Wq : (mat == 1) ? Wk : Wv;
    const float* bsrc = (mat == 0) ? bq : (mat == 1) ? bk : bv;
    const float sc = (mat == 0) ? QSCALE : 1.0f;
    const int r0b = (pb & 127) * 32;

    // self-convert W: thread t covers source elems [t*64, t*64+64)
    // Ws: fragment-ordered, lane-contiguous: elem (j0,kk,c,q,e) at
    //   (j0*4+kk)*512 + q*128 + c*8 + e   (lane (c,q) reads 16B at lane*16)
    {
        const int base = t * 64;
#pragma unroll
        for (int i = 0; i < 16; ++i) {
            const int off = base + i * 4;
            float4 v = *(const float4*)(Wsrc + off);
            ushort4 o;
            o.x = f2bf(v.x * sc); o.y = f2bf(v.y * sc);
            o.z = f2bf(v.z * sc); o.w = f2bf(v.w * sc);
            const int j = off >> 7, k0 = off & 127;
            const int j0 = j >> 4, c2 = j & 15, kk = k0 >> 5, qq = (k0 >> 3) & 3;
            *(ushort4*)(Ws + (j0 * 4 + kk) * 512 + qq * 128 + c2 * 8 + (k0 & 7)) = o;
        }
    }

    // stage X coalesced: thread -> row t>>3, 16 cols at (t&7)*16
    {
        const int r = t >> 3, cb = (t & 7) * 16;
        const float* Xr = X + (size_t)(r0b + r) * HS + cb;
#pragma unroll
        for (int seg = 0; seg < 4; ++seg) {
            float4 f = *(const float4*)(Xr + seg * 4);
            ushort4 u;
            u.x = f2bf(f.x); u.y = f2bf(f.y); u.z = f2bf(f.z); u.w = f2bf(f.w);
            *(ushort4*)(Xs + r * CSTR + cb + seg * 4) = u;
        }
    }
    __syncthreads();

    const int wv = t >> 6, lane = t & 63;
    const int c = lane & 15, q = lane >> 4;
    const int rw = (wv & 1) * 16;        // wave row offset in block
    const int j0b = (wv >> 1) * 4;       // wave col group (4 j0 of 16 cols)

    bf16x8 af[4];
#pragma unroll
    for (int kk = 0; kk < 4; ++kk)
        af[kk] = *(const bf16x8*)(Xs + (rw + c) * CSTR + kk * 32 + q * 8);

    const f32x4 zero = {0.f, 0.f, 0.f, 0.f};
#pragma unroll
    for (int jj = 0; jj < 4; ++jj) {
        const int j0 = j0b + jj;
        f32x4 acc = zero;
#pragma unroll
        for (int kk = 0; kk < 4; ++kk) {
            bf16x8 bf = *(const bf16x8*)(Ws + (j0 * 4 + kk) * 512 + q * 128 + c * 8);
            acc = __builtin_amdgcn_mfma_f32_16x16x32_bf16(af[kk], bf, acc, 0, 0, 0);
        }
        const float bias = bsrc[j0 * 16 + c] * sc;
#pragma unroll
        for (int r = 0; r < 4; ++r)
            Cs[(rw + 4 * q + r) * CSTR + j0 * 16 + c] = f2bf(acc[r] + bias);
    }
    __syncthreads();

    if (mat < 2) {
        u16* dst = (mat == 0) ? Qbh : Kbh;
        const int h8 = t >> 5, r = t & 31;
        const u16* src = Cs + r * CSTR + h8 * 16;
        int drow = r0b + r;
        if (mat == 1) {   // permuted K row slot within the 64-row block
            const int k = (r0b & 32) + r;
            const int slot = ((k >> 5) * 2 + ((k >> 2) & 1)) * 16
                           + ((k >> 3) & 3) * 4 + (k & 3);
            drow = (r0b & ~63) + slot;
        }
        u16* dp = dst + (size_t)h8 * (NA * 16) + (size_t)drow * 16;
        *(bf16x8*)(dp)     = *(const bf16x8*)(src);
        *(bf16x8*)(dp + 8) = *(const bf16x8*)(src + 8);
    } else {
        const int d = t >> 1, s = t & 1;
        const int kb = r0b >> 6, ko = (r0b & 32) + s * 16;
        ushort8 v0, v1;
#pragma unroll
        for (int jj = 0; jj < 8; ++jj) v0[jj] = Cs[(s * 16 + jj) * CSTR + d];
#pragma unroll
        for (int jj = 0; jj < 8; ++jj) v1[jj] = Cs[(s * 16 + 8 + jj) * CSTR + d];
        u16* dp = VtB + (size_t)kb * 8192 + d * 64 + ko;
        *(ushort8*)(dp)     = v0;
        *(ushort8*)(dp + 8) = v1;
    }
}

// ---------------------------------------------------------------------------
// Kernel 2: attention partials — EXACT round-2/4/7 body (passed r2, r4, r7).
// FROZEN: two semantically-equivalent rewrites of this loop (r3, r6) broke
// numerics; do not restructure register lifetimes here.
// Grid (256 tiles, 4 key-splits), 512 thr = 8 waves, wave = one head.
// P register-resident via the K-row permutation. Per iter: 4 ST MFMA ->
// 16 exp2 -> 8 cvt_pk -> mask AND -> 4 PV/L MFMA, all in regs.
// part[tile][split][head][272] = { O 16x16 f32, l 16 f32 }.
// ---------------------------------------------------------------------------
__global__ __launch_bounds__(512, 4) void attn(
    const u64* __restrict__ Mp,
    const u16* __restrict__ Qbh, const u16* __restrict__ Kbh, const u16* __restrict__ VtB,
    float* __restrict__ part)
{
    __shared__ __align__(8)  u64 Mwp[16 * 17];   // [query][word], padded stride
    __shared__ __align__(8)  u64 Mtab[16];       // nibble -> {lo16|hi16} x2 expand

    const int t = threadIdx.x;
    const int h = t >> 6;        // wave = head
    const int lane = t & 63;
    const int c = lane & 15;
    const int q = lane >> 4;
    const int tile = blockIdx.x, split = blockIdx.y;
    const int i0 = tile * 16;
    const int kt0 = split * 1024;

    // stage packed mask words: rows i0..i0+15, words split*16..+15
    if (t < 256) {
        const int row = t >> 4, w = t & 15;
        Mwp[row * 17 + w] = Mp[(size_t)(i0 + row) * 64 + (kt0 >> 6) + w];
    }
    if (t < 16) {
        const unsigned lo = ((t & 1) ? 0xFFFFu : 0u) | ((t & 2) ? 0xFFFF0000u : 0u);
        const unsigned hi = ((t & 4) ? 0xFFFFu : 0u) | ((t & 8) ? 0xFFFF0000u : 0u);
        Mtab[t] = (u64)lo | ((u64)hi << 32);
    }

    const u16* Qh = Qbh + (size_t)h * (NA * 16);
    const u16* Kh = Kbh + (size_t)h * (NA * 16);

    // Q B-fragment (K-halves duplicated; x2 folded into QSCALE); contiguous.
    const bf16x8 qf = *(const bf16x8*)(Qh + (size_t)(i0 + c) * 16 + (q & 1) * 8);

    // ones B-fragment for the lsum MFMA (all lanes = 1.0bf16)
    bf16x8 ones;
#pragma unroll
    for (int i = 0; i < 8; ++i) ones[i] = (short)0x3F80;

    __syncthreads();

    const f32x4 zero = {0.f, 0.f, 0.f, 0.f};
    f32x4 Oacc = zero;
    f32x4 Lacc = zero;

    // prologue: kf for iter 0 (rows are permuted slots; addresses natural)
    bf16x8 kf[4];
#pragma unroll
    for (int t4 = 0; t4 < 4; ++t4)
        kf[t4] = *(const bf16x8*)(Kh + (size_t)(kt0 + t4 * 16 + c) * 16 + (q & 1) * 8);

#pragma unroll 1
    for (int it = 0; it < 16; ++it) {
        const int kt = kt0 + it * 64;
        const u16* Vb = VtB + (size_t)(kt >> 6) * 8192 + (h * 16 + c) * 64;

        // V B-fragments (contiguous 1KB per load across the wave)
        bf16x8 vf0 = *(const bf16x8*)(Vb + q * 8);
        bf16x8 vf1 = *(const bf16x8*)(Vb + 32 + q * 8);

        // S^T tiles; permuted K => lane (c,q) reg r = S[q_row c][key B(t4)+8q+r]
        f32x4 ST[4];
        __builtin_amdgcn_s_setprio(1);
#pragma unroll
        for (int t4 = 0; t4 < 4; ++t4)
            ST[t4] = __builtin_amdgcn_mfma_f32_16x16x32_bf16(kf[t4], qf, zero, 0, 0, 0);
        __builtin_amdgcn_s_setprio(0);

        // prefetch next iter's kf (wraps to kt0 on last iter; data unused)
        const int ktn = kt0 + ((it + 1) & 15) * 64;
#pragma unroll
        for (int t4 = 0; t4 < 4; ++t4)
            kf[t4] = *(const bf16x8*)(Kh + (size_t)(ktn + t4 * 16 + c) * 16 + (q & 1) * 8);

        // mask bits, natural order: key B(t4)+8q+r; B = 32*(t4>>1)+4*(t4&1)
        const u64 w = Mwp[c * 17 + it];
        const unsigned wa = (unsigned)(w >> (8 * q));          // keys 8q+...
        const unsigned wb = (unsigned)(w >> (32 + 8 * q));     // keys 32+8q+...

        unsigned pl[4], ph[4];
#pragma unroll
        for (int t4 = 0; t4 < 4; ++t4) {
            const unsigned nib = (((t4 & 2) ? wb : wa) >> ((t4 & 1) * 4)) & 15u;
            float p0 = __builtin_amdgcn_exp2f(ST[t4][0]);
            float p1 = __builtin_amdgcn_exp2f(ST[t4][1]);
            float p2 = __builtin_amdgcn_exp2f(ST[t4][2]);
            float p3 = __builtin_amdgcn_exp2f(ST[t4][3]);
            unsigned lo, hi;
            asm("v_cvt_pk_bf16_f32 %0, %1, %2" : "=v"(lo) : "v"(p0), "v"(p1));
            asm("v_cvt_pk_bf16_f32 %0, %1, %2" : "=v"(hi) : "v"(p2), "v"(p3));
            const u64 mex = Mtab[nib];           // conflict-light 16-entry table
            pl[t4] = lo & (unsigned)mex;
            ph[t4] = hi & (unsigned)(mex >> 32);
        }
        const u32x4 a0 = { pl[0], ph[0], pl[1], ph[1] };   // keys 8q+0..7
        const u32x4 a1 = { pl[2], ph[2], pl[3], ph[3] };   // keys 32+8q+0..7
        const bf16x8 pf0 = __builtin_bit_cast(bf16x8, a0);
        const bf16x8 pf1 = __builtin_bit_cast(bf16x8, a1);

        // O += P @ V ; L += P @ ones (masked row-sums)
        __builtin_amdgcn_s_setprio(1);
        Oacc = __builtin_amdgcn_mfma_f32_16x16x32_bf16(pf0, vf0, Oacc, 0, 0, 0);
        Oacc = __builtin_amdgcn_mfma_f32_16x16x32_bf16(pf1, vf1, Oacc, 0, 0, 0);
        Lacc = __builtin_amdgcn_mfma_f32_16x16x32_bf16(pf0, ones, Lacc, 0, 0, 0);
        Lacc = __builtin_amdgcn_mfma_f32_16x16x32_bf16(pf1, ones, Lacc, 0, 0, 0);
        __builtin_amdgcn_s_setprio(0);
    }

    float* base = part + (size_t)((tile * 4 + split) * 8 + h) * 272;
#pragma unroll
    for (int r = 0; r < 4; ++r)
        base[(4 * q + r) * 16 + c] = Oacc[r];
    // Lacc: lane (c,q) reg r holds l[4q+r] (all c identical); c==0 lanes write
    if (c == 0) {
#pragma unroll
        for (int r = 0; r < 4; ++r)
            base[256 + 4 * q + r] = Lacc[r];
    }
}

// ---------------------------------------------------------------------------
// Kernel 3: combine 4 split partials, normalize, output projection via MFMA.
// (round-4/7 proven body; WoF fragment table, read path proven round 5/7)
// ---------------------------------------------------------------------------
__global__ __launch_bounds__(256) void reduce_out(
    const float* __restrict__ part, const u16* __restrict__ WoF,
    float* __restrict__ out)
{
    __shared__ __align__(16) u16 xs[16 * CSTR];

    const int t = threadIdx.x;
    const int tile = blockIdx.x;
    const int i0 = tile * 16;
    const float* Pt = part + (size_t)tile * 4 * 8 * 272;

    {
        const int i = t >> 4, d = t & 15;
#pragma unroll
        for (int h = 0; h < 8; ++h) {
            float os = 0.f, ls = 0.f;
#pragma unroll
            for (int s = 0; s < 4; ++s) {
                const float* b = Pt + (size_t)(s * 8 + h) * 272;
                os += b[i * 16 + d];
                ls += b[256 + i];
            }
            xs[i * CSTR + h * 16 + d] = f2bf(os / ls);
        }
    }
    __syncthreads();

    const int wv = t >> 6, lane = t & 63;
    const int c = lane & 15, q = lane >> 4;

    bf16x8 af[4];
#pragma unroll
    for (int kk = 0; kk < 4; ++kk)
        af[kk] = *(const bf16x8*)(xs + c * CSTR + kk * 32 + q * 8);

    const f32x4 zero = {0.f, 0.f, 0.f, 0.f};
#pragma unroll
    for (int jj = 0; jj < 2; ++jj) {
        const int j0 = wv * 2 + jj;
        f32x4 acc = zero;
#pragma unroll
        for (int kk = 0; kk < 4; ++kk) {
            bf16x8 bf = *(const bf16x8*)(WoF + (j0 * 4 + kk) * 512 + c * 32 + q * 8);
            acc = __builtin_amdgcn_mfma_f32_16x16x32_bf16(af[kk], bf, acc, 0, 0, 0);
        }
#pragma unroll
        for (int r = 0; r < 4; ++r)
            out[(size_t)(i0 + 4 * q + r) * HS + j0 * 16 + c] = acc[r];
    }
}

extern "C" void kernel_launch(void* const* d_in, const int* in_sizes, int n_in,
                              void* d_out, int out_size, void* d_ws, size_t ws_size,
                              hipStream_t stream) {
    const float* query = (const float*)d_in[0];
    const float* key   = (const float*)d_in[1];
    const float* value = (const float*)d_in[2];
    const int*   mask  = (const int*)d_in[3];
    const float* Wq    = (const float*)d_in[4];
    const float* bq    = (const float*)d_in[5];
    const float* Wk    = (const float*)d_in[6];
    const float* bk    = (const float*)d_in[7];
    const float* Wv    = (const float*)d_in[8];
    const float* bv    = (const float*)d_in[9];
    const float* Wo    = (const float*)d_in[10];

    u16* Qbh = (u16*)d_ws;                     // 1 MB  [8][4096][16]
    u16* Kbh = Qbh + (size_t)NA * HS;          // 1 MB  [8][4096][16] (permuted)
    u16* VtB = Kbh + (size_t)NA * HS;          // 1 MB  [64][128][64]
    u16* WoF = VtB + (size_t)NA * HS;          // 32 KB (Wo fragments)
    u64*  Mp  = (u64*)(WoF + 16384);           // 2 MB   [4096][64] packed mask
    float* partb = (float*)(Mp + (size_t)NA * 64);  // 256*4*8*272 f32 = 8.9 MB

    proj_pack<<<1424, 256, 0, stream>>>(query, key, value, Wq, Wk, Wv, Wo,
                                        bq, bk, bv, mask,
                                        Qbh, Kbh, VtB, Mp, WoF);
    attn<<<dim3(256, 4), 512, 0, stream>>>(Mp, Qbh, Kbh, VtB, partb);
    reduce_out<<<256, 256, 0, stream>>>(partb, WoF, (float*)d_out);
}